// Round 1
// baseline (2825.867 us; speedup 1.0000x reference)
//
#include <hip/hip_runtime.h>
#include <math.h>
#include <stdint.h>

// Problem constants
#define B_   2
#define T_   1024
#define D_   1024
#define H_   16
#define DH_  64
#define M_   4096
#define V_   50257
#define L_   4
#define NTOK (B_*T_)   // 2048 rows

typedef _Float16 f16;
typedef __attribute__((ext_vector_type(8))) _Float16 half8;
typedef __attribute__((ext_vector_type(4))) _Float16 half4;
typedef __attribute__((ext_vector_type(4))) float   floatx4;

// ---------------- async global->LDS, 16B per lane ---------------------------
__device__ inline void async_ld16(const void* g, void* l) {
  void* gp = (void*)g;  // drop const
  __builtin_amdgcn_global_load_lds(
      (__attribute__((address_space(1))) void*)gp,
      (__attribute__((address_space(3))) void*)l, 16, 0, 0);
}

// ---------------- GEMM: C = A @ Bt^T (+bias, epilogue) ----------------------
// A  : [M,K]  f16 row-major (lda)
// Bt : [N,K]  f16 row-major (ldb)   (i.e. original W[K,N] transposed)
// LDS layout per operand: fragment-major, unit u=(q*BMorBN + row), 16B units.
enum { EPI_F16 = 0, EPI_GELU = 1, EPI_ADDF32 = 2, EPI_F32 = 3 };

template<int BM, int BN, int WM, int WN, int EPI>
__global__ __launch_bounds__(256) void gemm_bt(
    const f16* __restrict__ A, int lda,
    const f16* __restrict__ Bt, int ldb,
    void* __restrict__ Cv, int ldc,
    const float* __restrict__ bias,
    int Nsz, int K, float scale,
    int Z0, int64_t sa1, int64_t sa0, int64_t sb1, int64_t sb0,
    int64_t sc1, int64_t sc0)
{
  constexpr int MT = BM/(WM*16), NT = BN/(WN*16);
  __shared__ f16 lds[(BM+BN)*32];
  const int tid  = threadIdx.x;
  const int wave = tid >> 6, lane = tid & 63;
  const int quad = lane >> 4, r16 = lane & 15;

  // ---- block remap: bijective XCD chunking + N-panel-major tile walk ----
  // Dispatch order is x-fastest and round-robins the 8 XCDs. Remap so each
  // XCD owns a contiguous chunk of tiles, walked N-panel-major: the gy
  // M-blocks sharing one B panel run back-to-back on the SAME XCD -> the
  // panel stays in that XCD's private 4MB L2 instead of being refetched
  // from HBM (head GEMM: 16 re-reads of 103MB -> ~1 read).
  const int gx = gridDim.x, gy = gridDim.y;
  const int nblk = gx * gy;
  int lin = blockIdx.y * gx + blockIdx.x;
  {
    const int nx = 8;                      // XCDs on MI355X
    int q = nblk / nx, r = nblk % nx;
    int xcd = lin % nx, idx = lin / nx;
    lin = (xcd < r ? xcd*(q+1) : r*(q+1) + (xcd - r)*q) + idx;
  }
  const int tn = lin / gy, tm = lin % gy;  // N-panel-major
  const int m0 = tm*BM, n0 = tn*BN;

  const int z  = blockIdx.z;
  const int z1 = z / Z0, z0 = z % Z0;
  const f16* Ab = A  + z1*sa1 + z0*sa0;
  const f16* Bb = Bt + z1*sb1 + z0*sb0;
  const int64_t cbase = z1*sc1 + z0*sc0;
  const int wm = wave / WN, wn = wave % WN;

  floatx4 acc[MT][NT];
#pragma unroll
  for (int mt = 0; mt < MT; ++mt)
#pragma unroll
    for (int nt = 0; nt < NT; ++nt)
      acc[mt][nt] = (floatx4){0.f, 0.f, 0.f, 0.f};

  for (int kt = 0; kt < K; kt += 32) {
    __syncthreads();   // previous tile's ds_reads complete
    // stage A tile: BM*4 16B-units; chunk c = 64 units, one wave-instr each
#pragma unroll
    for (int i = 0; i < BM/64; ++i) {
      int c = i*4 + wave;
      int u = c*64 + lane;
      int q = u / BM, m = u % BM;
      const f16* gp = Ab + (int64_t)(m0+m)*lda + kt + q*8;
      async_ld16(gp, &lds[c*64*8]);          // wave-uniform LDS base
    }
    // stage B tile (row-clamped for N edge)
#pragma unroll
    for (int i = 0; i < BN/64; ++i) {
      int c = i*4 + wave;
      int u = c*64 + lane;
      int q = u / BN, n = u % BN;
      int gn = n0 + n; if (gn >= Nsz) gn = Nsz - 1;
      const f16* gp = Bb + (int64_t)gn*ldb + kt + q*8;
      async_ld16(gp, &lds[BM*32 + c*64*8]);
    }
    __syncthreads();   // vmcnt(0) drain + barrier

    half8 af[MT], bf[NT];
#pragma unroll
    for (int mt = 0; mt < MT; ++mt) {
      int ml = wm*(BM/WM) + mt*16 + r16;
      af[mt] = *(const half8*)&lds[(quad*BM + ml)*8];
    }
#pragma unroll
    for (int nt = 0; nt < NT; ++nt) {
      int nl = wn*(BN/WN) + nt*16 + r16;
      bf[nt] = *(const half8*)&lds[BM*32 + (quad*BN + nl)*8];
    }
#pragma unroll
    for (int mt = 0; mt < MT; ++mt)
#pragma unroll
      for (int nt = 0; nt < NT; ++nt)
        acc[mt][nt] = __builtin_amdgcn_mfma_f32_16x16x32_f16(af[mt], bf[nt], acc[mt][nt], 0, 0, 0);
  }

  // epilogue: C/D layout col=lane&15, row=quad*4+r
  f16*   C16 = (f16*)Cv;
  float* C32 = (float*)Cv;
#pragma unroll
  for (int mt = 0; mt < MT; ++mt) {
#pragma unroll
    for (int nt = 0; nt < NT; ++nt) {
      int col = n0 + wn*(BN/WN) + nt*16 + r16;
      if (col >= Nsz) continue;
      float bv = bias ? bias[col] : 0.f;
      int rowb = m0 + wm*(BM/WM) + mt*16 + quad*4;
#pragma unroll
      for (int k = 0; k < 4; ++k) {
        float v = acc[mt][nt][k]*scale + bv;
        int64_t idx = cbase + (int64_t)(rowb+k)*ldc + col;
        if constexpr (EPI == EPI_F16) {
          C16[idx] = (f16)v;
        } else if constexpr (EPI == EPI_GELU) {
          C16[idx] = (f16)(0.5f*v*(1.f + erff(v*0.70710678118f)));
        } else if constexpr (EPI == EPI_ADDF32) {
          C32[idx] += v;
        } else {
          C32[idx] = v;
        }
      }
    }
  }
}

// ---------------- embedding: h = tok_emb[x] + pos_emb -----------------------
__global__ __launch_bounds__(256) void embed_kernel(
    const int* __restrict__ x, const float* __restrict__ tok,
    const float* __restrict__ pos, float* __restrict__ h)
{
  int row = blockIdx.x;           // b*T + t
  int t = row & (T_-1);
  int token = x[row];
  float4 a = ((const float4*)(tok + (int64_t)token*D_))[threadIdx.x];
  float4 p = ((const float4*)(pos + (int64_t)t*D_))[threadIdx.x];
  float4 o = {a.x+p.x, a.y+p.y, a.z+p.z, a.w+p.w};
  ((float4*)(h + (int64_t)row*D_))[threadIdx.x] = o;
}

// ---------------- layernorm (fp32 in, f16 out) ------------------------------
__global__ __launch_bounds__(256) void ln_kernel(
    const float* __restrict__ x, const float* __restrict__ g,
    const float* __restrict__ b, f16* __restrict__ out)
{
  int row = blockIdx.x;
  float4 v = ((const float4*)(x + (int64_t)row*D_))[threadIdx.x];
  float s  = v.x+v.y+v.z+v.w;
  float ss = v.x*v.x+v.y*v.y+v.z*v.z+v.w*v.w;
  for (int o = 32; o > 0; o >>= 1) { s += __shfl_down(s, o); ss += __shfl_down(ss, o); }
  __shared__ float red[8];
  int wave = threadIdx.x >> 6, lane = threadIdx.x & 63;
  if (lane == 0) { red[wave] = s; red[4+wave] = ss; }
  __syncthreads();
  s  = red[0]+red[1]+red[2]+red[3];
  ss = red[4]+red[5]+red[6]+red[7];
  float mu   = s * (1.f/D_);
  float rstd = rsqrtf(ss*(1.f/D_) - mu*mu + 1e-5f);
  float4 gv = ((const float4*)g)[threadIdx.x];
  float4 bv = ((const float4*)b)[threadIdx.x];
  half4 ov = { (f16)((v.x-mu)*rstd*gv.x + bv.x),
               (f16)((v.y-mu)*rstd*gv.y + bv.y),
               (f16)((v.z-mu)*rstd*gv.z + bv.z),
               (f16)((v.w-mu)*rstd*gv.w + bv.w) };
  *(half4*)(out + (int64_t)row*D_ + threadIdx.x*4) = ov;
}

// ---------------- softmax over rows of S (fp32) -> P (f16) ------------------
__global__ __launch_bounds__(256) void softmax_kernel(
    const float* __restrict__ S, f16* __restrict__ P)
{
  int64_t row = blockIdx.x;
  float4 v = ((const float4*)(S + row*T_))[threadIdx.x];
  float m = fmaxf(fmaxf(v.x, v.y), fmaxf(v.z, v.w));
  for (int o = 32; o > 0; o >>= 1) m = fmaxf(m, __shfl_down(m, o));
  __shared__ float red[8];
  int wave = threadIdx.x >> 6, lane = threadIdx.x & 63;
  if (lane == 0) red[wave] = m;
  __syncthreads();
  m = fmaxf(fmaxf(red[0], red[1]), fmaxf(red[2], red[3]));
  float e0 = __expf(v.x-m), e1 = __expf(v.y-m), e2 = __expf(v.z-m), e3 = __expf(v.w-m);
  float s = e0+e1+e2+e3;
  for (int o = 32; o > 0; o >>= 1) s += __shfl_down(s, o);
  if (lane == 0) red[4+wave] = s;
  __syncthreads();
  s = red[4]+red[5]+red[6]+red[7];
  float inv = 1.f/s;
  half4 ov = { (f16)(e0*inv), (f16)(e1*inv), (f16)(e2*inv), (f16)(e3*inv) };
  *(half4*)(P + row*T_ + threadIdx.x*4) = ov;
}

// ---------------- W[K,N] fp32 -> WT[N,K] f16 --------------------------------
__global__ __launch_bounds__(256) void transpose_w(
    const float* __restrict__ W, f16* __restrict__ WT, int K, int N)
{
  __shared__ float tile[64][65];
  int n0 = blockIdx.x*64, k0 = blockIdx.y*64;
  int c = threadIdx.x & 63, rb = threadIdx.x >> 6;
#pragma unroll
  for (int i = 0; i < 16; ++i) {
    int r = rb*16 + i;
    int gk = k0 + r, gn = n0 + c;
    tile[r][c] = (gk < K && gn < N) ? W[(int64_t)gk*N + gn] : 0.f;
  }
  __syncthreads();
#pragma unroll
  for (int i = 0; i < 16; ++i) {
    int r = rb*16 + i;          // along N now
    int gn = n0 + r, gk = k0 + c;
    if (gn < N && gk < K) WT[(int64_t)gn*K + gk] = (f16)tile[c][r];
  }
}

// ---------------- V[b,t,h,dh] (f16, inside qkv buf) -> VT[b,h,dh,t] ---------
__global__ __launch_bounds__(256) void transpose_v(
    const f16* __restrict__ qkv, f16* __restrict__ vT)
{
  __shared__ f16 tile[64][66];
  int t0 = blockIdx.x*64;
  int bh = blockIdx.y;             // b*H + h
  int b = bh >> 4, h = bh & 15;
  const f16* v = qkv + (int64_t)2*NTOK*D_ + (int64_t)b*T_*D_ + h*DH_;
  int c = threadIdx.x & 63, rb = threadIdx.x >> 6;
#pragma unroll
  for (int i = 0; i < 16; ++i) {
    int tl = rb*16 + i;
    tile[tl][c] = v[(int64_t)(t0+tl)*D_ + c];
  }
  __syncthreads();
  f16* out = vT + (int64_t)bh*DH_*T_;
#pragma unroll
  for (int i = 0; i < 16; ++i) {
    int dh = rb*16 + i;
    out[(int64_t)dh*T_ + t0 + c] = tile[c][dh];
  }
}

// ---------------------------------------------------------------------------
extern "C" void kernel_launch(void* const* d_in, const int* in_sizes, int n_in,
                              void* d_out, int out_size, void* d_ws, size_t ws_size,
                              hipStream_t stream)
{
  const int*   x       = (const int*)  d_in[0];
  const float* tok_emb = (const float*)d_in[1];
  const float* pos_emb = (const float*)d_in[2];
  const float* ln1_g   = (const float*)d_in[3];
  const float* ln1_b   = (const float*)d_in[4];
  const float* qkv_w   = (const float*)d_in[5];
  const float* qkv_b   = (const float*)d_in[6];
  const float* out_w   = (const float*)d_in[7];
  const float* out_b   = (const float*)d_in[8];
  const float* ln2_g   = (const float*)d_in[9];
  const float* ln2_b   = (const float*)d_in[10];
  const float* wi_w    = (const float*)d_in[11];
  const float* wi_b    = (const float*)d_in[12];
  const float* wo_w    = (const float*)d_in[13];
  const float* wo_b    = (const float*)d_in[14];
  const float* lnf_g   = (const float*)d_in[15];
  const float* lnf_b   = (const float*)d_in[16];
  const float* head_w  = (const float*)d_in[17];
  const float* head_b  = (const float*)d_in[18];
  float* out = (float*)d_out;

  // ---- workspace layout (bytes) ----
  char* ws = (char*)d_ws;
  size_t off = 0;
  f16* headT = (f16*)(ws + off); off += (size_t)V_*D_*2;      // 102,926,336
  f16* xbf   = (f16*)(ws + off); off += (size_t)NTOK*D_*2;    // ln output
  f16* qkvb  = (f16*)(ws + off); off += (size_t)NTOK*3*D_*2;  // qkv GEMM out
  f16* vT    = (f16*)(ws + off); off += (size_t)NTOK*D_*2;
  f16* inner = (f16*)(ws + off); off += (size_t)NTOK*D_*2;
  f16* mid   = (f16*)(ws + off); off += (size_t)NTOK*M_*2;
  float* h   = (float*)(ws + off); off += (size_t)NTOK*D_*4;
  (void)ws_size; (void)in_sizes; (void)n_in; (void)out_size;

  // ---- scratch carved from the front of d_out (dead before head GEMM) ----
  char* ob = (char*)d_out;
  f16*   wT = (f16*)ob;                       // 4 layers x 12,582,912 f16 = 96.5 MB
  float* S  = (float*)(ob + 100663296);       // 32*1024*1024 fp32 = 134.2 MB
  f16*   P  = (f16*)  (ob + 234881024);       // 67.1 MB ; ends 302 MB < 412 MB

  const size_t wlsz = 12582912;  // elements per layer in wT
  const int64_t TD  = (int64_t)T_*D_;
  const int64_t TT  = (int64_t)T_*T_;
  const int64_t HTT = (int64_t)H_*TT;

  // ---- weight transposes (fp32 -> f16, [K,N] -> [N,K]) ----
  for (int l = 0; l < L_; ++l) {
    f16* qkvT_l = wT + l*wlsz;
    f16* outT_l = qkvT_l + (size_t)3*D_*D_;
    f16* wiT_l  = outT_l + (size_t)D_*D_;
    f16* woT_l  = wiT_l  + (size_t)D_*M_;
    transpose_w<<<dim3(3*D_/64, D_/64), 256, 0, stream>>>(qkv_w + (size_t)l*D_*3*D_, qkvT_l, D_, 3*D_);
    transpose_w<<<dim3(D_/64,   D_/64), 256, 0, stream>>>(out_w + (size_t)l*D_*D_,  outT_l, D_, D_);
    transpose_w<<<dim3(M_/64,   D_/64), 256, 0, stream>>>(wi_w  + (size_t)l*D_*M_,  wiT_l,  D_, M_);
    transpose_w<<<dim3(D_/64,   M_/64), 256, 0, stream>>>(wo_w  + (size_t)l*M_*D_,  woT_l,  M_, D_);
  }
  transpose_w<<<dim3((V_+63)/64, D_/64), 256, 0, stream>>>(head_w, headT, D_, V_);

  // ---- embedding ----
  embed_kernel<<<NTOK, 256, 0, stream>>>(x, tok_emb, pos_emb, h);

  // ---- layers ----
  for (int l = 0; l < L_; ++l) {
    f16* qkvT_l = wT + l*wlsz;
    f16* outT_l = qkvT_l + (size_t)3*D_*D_;
    f16* wiT_l  = outT_l + (size_t)D_*D_;
    f16* woT_l  = wiT_l  + (size_t)D_*M_;

    ln_kernel<<<NTOK, 256, 0, stream>>>(h, ln1_g + l*D_, ln1_b + l*D_, xbf);

    // qkv: [2048,1024] @ [1024,3072] -> qkvb f16 [2048,3072]
    gemm_bt<128,128,2,2,EPI_F16><<<dim3(3*D_/128, NTOK/128, 1), 256, 0, stream>>>(
        xbf, D_, qkvT_l, D_, qkvb, 3*D_, qkv_b + (size_t)l*3*D_, 3*D_, D_, 1.f,
        1, 0,0, 0,0, 0,0);

    transpose_v<<<dim3(T_/64, B_*H_), 256, 0, stream>>>(qkvb, vT);

    // scores: per (b,h): Q[1024,64] @ K^T -> S fp32, scaled by 1/8
    gemm_bt<128,128,2,2,EPI_F32><<<dim3(T_/128, T_/128, B_*H_), 256, 0, stream>>>(
        qkvb, D_, qkvb + (size_t)NTOK*D_, D_, S, T_, nullptr, T_, DH_, 0.125f,
        H_, TD, 64, TD, 64, HTT, TT);

    softmax_kernel<<<B_*H_*T_, 256, 0, stream>>>(S, P);

    // PV: per (b,h): P[1024,1024] @ V -> inner[b,t,h*64+dh] f16
    gemm_bt<128,64,4,1,EPI_F16><<<dim3(1, T_/128, B_*H_), 256, 0, stream>>>(
        P, T_, vT, T_, inner, D_, nullptr, DH_, T_, 1.f,
        H_, HTT, TT, (int64_t)H_*DH_*T_, (int64_t)DH_*T_, TD, 64);

    // out proj: h += inner @ out_w + out_b
    gemm_bt<128,64,4,1,EPI_ADDF32><<<dim3(D_/64, NTOK/128, 1), 256, 0, stream>>>(
        inner, D_, outT_l, D_, h, D_, out_b + (size_t)l*D_, D_, D_, 1.f,
        1, 0,0, 0,0, 0,0);

    ln_kernel<<<NTOK, 256, 0, stream>>>(h, ln2_g + l*D_, ln2_b + l*D_, xbf);

    // wi + exact GELU -> mid f16 [2048,4096]
    gemm_bt<128,128,2,2,EPI_GELU><<<dim3(M_/128, NTOK/128, 1), 256, 0, stream>>>(
        xbf, D_, wiT_l, D_, mid, M_, wi_b + (size_t)l*M_, M_, D_, 1.f,
        1, 0,0, 0,0, 0,0);

    // wo: h += mid @ wo_w + wo_b
    gemm_bt<128,64,4,1,EPI_ADDF32><<<dim3(D_/64, NTOK/128, 1), 256, 0, stream>>>(
        mid, M_, woT_l, M_, h, D_, wo_b + (size_t)l*D_, D_, M_, 1.f,
        1, 0,0, 0,0, 0,0);
  }

  // ---- final LN + head (writes all of d_out; scratch regions now dead) ----
  ln_kernel<<<NTOK, 256, 0, stream>>>(h, lnf_g, lnf_b, xbf);
  gemm_bt<128,128,2,2,EPI_F32><<<dim3((V_+127)/128, NTOK/128, 1), 256, 0, stream>>>(
      xbf, D_, headT, D_, out, V_, head_b, V_, D_, 1.f,
      1, 0,0, 0,0, 0,0);
}

// Round 2
// 2720.407 us; speedup vs baseline: 1.0388x; 1.0388x over previous
//
#include <hip/hip_runtime.h>
#include <math.h>
#include <stdint.h>

// Problem constants
#define B_   2
#define T_   1024
#define D_   1024
#define H_   16
#define DH_  64
#define M_   4096
#define V_   50257
#define L_   4
#define NTOK (B_*T_)   // 2048 rows

typedef _Float16 f16;
typedef __attribute__((ext_vector_type(8))) _Float16 half8;
typedef __attribute__((ext_vector_type(4))) _Float16 half4;
typedef __attribute__((ext_vector_type(4))) float   floatx4;

// ---------------- async global->LDS, 16B per lane ---------------------------
__device__ inline void async_ld16(const void* g, void* l) {
  void* gp = (void*)g;  // drop const
  __builtin_amdgcn_global_load_lds(
      (__attribute__((address_space(1))) void*)gp,
      (__attribute__((address_space(3))) void*)l, 16, 0, 0);
}

// ---------------- GEMM: C = A @ Bt^T (+bias, epilogue) ----------------------
// A  : [M,K]  f16 row-major (lda)
// Bt : [N,K]  f16 row-major (ldb)   (i.e. original W[K,N] transposed)
// LDS layout per operand: fragment-major, unit u=(q*BMorBN + row), 16B units.
// T3-minimum 2-phase pipeline: double-buffered LDS; next tile's
// global_load_lds issued BEFORE current tile's ds_read+MFMA; single
// __syncthreads (vmcnt(0)+barrier) per K-step at the END so the prefetch
// latency hides under compute.
enum { EPI_F16 = 0, EPI_GELU = 1, EPI_ADDF32 = 2, EPI_F32 = 3 };

template<int BM, int BN, int WM, int WN, int EPI>
__global__ __launch_bounds__(256) void gemm_bt(
    const f16* __restrict__ A, int lda,
    const f16* __restrict__ Bt, int ldb,
    void* __restrict__ Cv, int ldc,
    const float* __restrict__ bias,
    int Nsz, int K, float scale,
    int Z0, int64_t sa1, int64_t sa0, int64_t sb1, int64_t sb0,
    int64_t sc1, int64_t sc0)
{
  constexpr int MT = BM/(WM*16), NT = BN/(WN*16);
  constexpr int HALF = (BM+BN)*32;          // f16 elems per LDS buffer
  __shared__ f16 lds[2*HALF];
  const int tid  = threadIdx.x;
  const int wave = tid >> 6, lane = tid & 63;
  const int quad = lane >> 4, r16 = lane & 15;

  // ---- block remap: bijective XCD chunking + N-panel-major tile walk ----
  // (Round 1: FETCH_SIZE 897MB -> 300MB on head GEMM; keeps B panels in the
  //  owning XCD's private L2.)
  const int gx = gridDim.x, gy = gridDim.y;
  const int nblk = gx * gy;
  int lin = blockIdx.y * gx + blockIdx.x;
  {
    const int nx = 8;                      // XCDs on MI355X
    int q = nblk / nx, r = nblk % nx;
    int xcd = lin % nx, idx = lin / nx;
    lin = (xcd < r ? xcd*(q+1) : r*(q+1) + (xcd - r)*q) + idx;
  }
  const int tn = lin / gy, tm = lin % gy;  // N-panel-major
  const int m0 = tm*BM, n0 = tn*BN;

  const int z  = blockIdx.z;
  const int z1 = z / Z0, z0 = z % Z0;
  const f16* Ab = A  + z1*sa1 + z0*sa0;
  const f16* Bb = Bt + z1*sb1 + z0*sb0;
  const int64_t cbase = z1*sc1 + z0*sc0;
  const int wm = wave / WN, wn = wave % WN;

  floatx4 acc[MT][NT];
#pragma unroll
  for (int mt = 0; mt < MT; ++mt)
#pragma unroll
    for (int nt = 0; nt < NT; ++nt)
      acc[mt][nt] = (floatx4){0.f, 0.f, 0.f, 0.f};

  // stage one K-tile (kt) into LDS buffer `buf`
  auto STAGE = [&](int buf, int kt) {
    // A tile: BM*4 16B-units; chunk c = 64 units, one wave-instr each
#pragma unroll
    for (int i = 0; i < BM/64; ++i) {
      int c = i*4 + wave;
      int u = c*64 + lane;
      int q = u / BM, m = u % BM;
      const f16* gp = Ab + (int64_t)(m0+m)*lda + kt + q*8;
      async_ld16(gp, &lds[buf*HALF + c*64*8]);        // wave-uniform LDS base
    }
    // B tile (row-clamped for N edge)
#pragma unroll
    for (int i = 0; i < BN/64; ++i) {
      int c = i*4 + wave;
      int u = c*64 + lane;
      int q = u / BN, n = u % BN;
      int gn = n0 + n; if (gn >= Nsz) gn = Nsz - 1;
      const f16* gp = Bb + (int64_t)gn*ldb + kt + q*8;
      async_ld16(gp, &lds[buf*HALF + BM*32 + c*64*8]);
    }
  };

  const int nk = K >> 5;
  STAGE(0, 0);
  __syncthreads();            // vmcnt(0) drain + barrier: buf0 ready
  int cur = 0;

  for (int t = 0; t < nk; ++t) {
    if (t + 1 < nk) STAGE(cur ^ 1, (t + 1) << 5);   // prefetch next tile

    half8 af[MT], bf[NT];
#pragma unroll
    for (int mt = 0; mt < MT; ++mt) {
      int ml = wm*(BM/WM) + mt*16 + r16;
      af[mt] = *(const half8*)&lds[cur*HALF + (quad*BM + ml)*8];
    }
#pragma unroll
    for (int nt = 0; nt < NT; ++nt) {
      int nl = wn*(BN/WN) + nt*16 + r16;
      bf[nt] = *(const half8*)&lds[cur*HALF + BM*32 + (quad*BN + nl)*8];
    }
#pragma unroll
    for (int mt = 0; mt < MT; ++mt)
#pragma unroll
      for (int nt = 0; nt < NT; ++nt)
        acc[mt][nt] = __builtin_amdgcn_mfma_f32_16x16x32_f16(af[mt], bf[nt], acc[mt][nt], 0, 0, 0);

    __syncthreads();          // vmcnt(0): next tile landed; all reads of cur done
    cur ^= 1;
  }

  // epilogue: C/D layout col=lane&15, row=quad*4+r
  f16*   C16 = (f16*)Cv;
  float* C32 = (float*)Cv;
#pragma unroll
  for (int mt = 0; mt < MT; ++mt) {
#pragma unroll
    for (int nt = 0; nt < NT; ++nt) {
      int col = n0 + wn*(BN/WN) + nt*16 + r16;
      if (col >= Nsz) continue;
      float bv = bias ? bias[col] : 0.f;
      int rowb = m0 + wm*(BM/WM) + mt*16 + quad*4;
#pragma unroll
      for (int k = 0; k < 4; ++k) {
        float v = acc[mt][nt][k]*scale + bv;
        int64_t idx = cbase + (int64_t)(rowb+k)*ldc + col;
        if constexpr (EPI == EPI_F16) {
          C16[idx] = (f16)v;
        } else if constexpr (EPI == EPI_GELU) {
          C16[idx] = (f16)(0.5f*v*(1.f + erff(v*0.70710678118f)));
        } else if constexpr (EPI == EPI_ADDF32) {
          C32[idx] += v;
        } else {
          C32[idx] = v;
        }
      }
    }
  }
}

// ---------------- embedding: h = tok_emb[x] + pos_emb -----------------------
__global__ __launch_bounds__(256) void embed_kernel(
    const int* __restrict__ x, const float* __restrict__ tok,
    const float* __restrict__ pos, float* __restrict__ h)
{
  int row = blockIdx.x;           // b*T + t
  int t = row & (T_-1);
  int token = x[row];
  float4 a = ((const float4*)(tok + (int64_t)token*D_))[threadIdx.x];
  float4 p = ((const float4*)(pos + (int64_t)t*D_))[threadIdx.x];
  float4 o = {a.x+p.x, a.y+p.y, a.z+p.z, a.w+p.w};
  ((float4*)(h + (int64_t)row*D_))[threadIdx.x] = o;
}

// ---------------- layernorm (fp32 in, f16 out) ------------------------------
__global__ __launch_bounds__(256) void ln_kernel(
    const float* __restrict__ x, const float* __restrict__ g,
    const float* __restrict__ b, f16* __restrict__ out)
{
  int row = blockIdx.x;
  float4 v = ((const float4*)(x + (int64_t)row*D_))[threadIdx.x];
  float s  = v.x+v.y+v.z+v.w;
  float ss = v.x*v.x+v.y*v.y+v.z*v.z+v.w*v.w;
  for (int o = 32; o > 0; o >>= 1) { s += __shfl_down(s, o); ss += __shfl_down(ss, o); }
  __shared__ float red[8];
  int wave = threadIdx.x >> 6, lane = threadIdx.x & 63;
  if (lane == 0) { red[wave] = s; red[4+wave] = ss; }
  __syncthreads();
  s  = red[0]+red[1]+red[2]+red[3];
  ss = red[4]+red[5]+red[6]+red[7];
  float mu   = s * (1.f/D_);
  float rstd = rsqrtf(ss*(1.f/D_) - mu*mu + 1e-5f);
  float4 gv = ((const float4*)g)[threadIdx.x];
  float4 bv = ((const float4*)b)[threadIdx.x];
  half4 ov = { (f16)((v.x-mu)*rstd*gv.x + bv.x),
               (f16)((v.y-mu)*rstd*gv.y + bv.y),
               (f16)((v.z-mu)*rstd*gv.z + bv.z),
               (f16)((v.w-mu)*rstd*gv.w + bv.w) };
  *(half4*)(out + (int64_t)row*D_ + threadIdx.x*4) = ov;
}

// ---------------- softmax over rows of S (fp32) -> P (f16) ------------------
__global__ __launch_bounds__(256) void softmax_kernel(
    const float* __restrict__ S, f16* __restrict__ P)
{
  int64_t row = blockIdx.x;
  float4 v = ((const float4*)(S + row*T_))[threadIdx.x];
  float m = fmaxf(fmaxf(v.x, v.y), fmaxf(v.z, v.w));
  for (int o = 32; o > 0; o >>= 1) m = fmaxf(m, __shfl_down(m, o));
  __shared__ float red[8];
  int wave = threadIdx.x >> 6, lane = threadIdx.x & 63;
  if (lane == 0) red[wave] = m;
  __syncthreads();
  m = fmaxf(fmaxf(red[0], red[1]), fmaxf(red[2], red[3]));
  float e0 = __expf(v.x-m), e1 = __expf(v.y-m), e2 = __expf(v.z-m), e3 = __expf(v.w-m);
  float s = e0+e1+e2+e3;
  for (int o = 32; o > 0; o >>= 1) s += __shfl_down(s, o);
  if (lane == 0) red[4+wave] = s;
  __syncthreads();
  s = red[4]+red[5]+red[6]+red[7];
  float inv = 1.f/s;
  half4 ov = { (f16)(e0*inv), (f16)(e1*inv), (f16)(e2*inv), (f16)(e3*inv) };
  *(half4*)(P + row*T_ + threadIdx.x*4) = ov;
}

// ---------------- W[K,N] fp32 -> WT[N,K] f16 --------------------------------
__global__ __launch_bounds__(256) void transpose_w(
    const float* __restrict__ W, f16* __restrict__ WT, int K, int N)
{
  __shared__ float tile[64][65];
  int n0 = blockIdx.x*64, k0 = blockIdx.y*64;
  int c = threadIdx.x & 63, rb = threadIdx.x >> 6;
#pragma unroll
  for (int i = 0; i < 16; ++i) {
    int r = rb*16 + i;
    int gk = k0 + r, gn = n0 + c;
    tile[r][c] = (gk < K && gn < N) ? W[(int64_t)gk*N + gn] : 0.f;
  }
  __syncthreads();
#pragma unroll
  for (int i = 0; i < 16; ++i) {
    int r = rb*16 + i;          // along N now
    int gn = n0 + r, gk = k0 + c;
    if (gn < N && gk < K) WT[(int64_t)gn*K + gk] = (f16)tile[c][r];
  }
}

// ---------------- V[b,t,h,dh] (f16, inside qkv buf) -> VT[b,h,dh,t] ---------
__global__ __launch_bounds__(256) void transpose_v(
    const f16* __restrict__ qkv, f16* __restrict__ vT)
{
  __shared__ f16 tile[64][66];
  int t0 = blockIdx.x*64;
  int bh = blockIdx.y;             // b*H + h
  int b = bh >> 4, h = bh & 15;
  const f16* v = qkv + (int64_t)2*NTOK*D_ + (int64_t)b*T_*D_ + h*DH_;
  int c = threadIdx.x & 63, rb = threadIdx.x >> 6;
#pragma unroll
  for (int i = 0; i < 16; ++i) {
    int tl = rb*16 + i;
    tile[tl][c] = v[(int64_t)(t0+tl)*D_ + c];
  }
  __syncthreads();
  f16* out = vT + (int64_t)bh*DH_*T_;
#pragma unroll
  for (int i = 0; i < 16; ++i) {
    int dh = rb*16 + i;
    out[(int64_t)dh*T_ + t0 + c] = tile[c][dh];
  }
}

// ---------------------------------------------------------------------------
extern "C" void kernel_launch(void* const* d_in, const int* in_sizes, int n_in,
                              void* d_out, int out_size, void* d_ws, size_t ws_size,
                              hipStream_t stream)
{
  const int*   x       = (const int*)  d_in[0];
  const float* tok_emb = (const float*)d_in[1];
  const float* pos_emb = (const float*)d_in[2];
  const float* ln1_g   = (const float*)d_in[3];
  const float* ln1_b   = (const float*)d_in[4];
  const float* qkv_w   = (const float*)d_in[5];
  const float* qkv_b   = (const float*)d_in[6];
  const float* out_w   = (const float*)d_in[7];
  const float* out_b   = (const float*)d_in[8];
  const float* ln2_g   = (const float*)d_in[9];
  const float* ln2_b   = (const float*)d_in[10];
  const float* wi_w    = (const float*)d_in[11];
  const float* wi_b    = (const float*)d_in[12];
  const float* wo_w    = (const float*)d_in[13];
  const float* wo_b    = (const float*)d_in[14];
  const float* lnf_g   = (const float*)d_in[15];
  const float* lnf_b   = (const float*)d_in[16];
  const float* head_w  = (const float*)d_in[17];
  const float* head_b  = (const float*)d_in[18];
  float* out = (float*)d_out;

  // ---- workspace layout (bytes) ----
  char* ws = (char*)d_ws;
  size_t off = 0;
  f16* headT = (f16*)(ws + off); off += (size_t)V_*D_*2;      // 102,926,336
  f16* xbf   = (f16*)(ws + off); off += (size_t)NTOK*D_*2;    // ln output
  f16* qkvb  = (f16*)(ws + off); off += (size_t)NTOK*3*D_*2;  // qkv GEMM out
  f16* vT    = (f16*)(ws + off); off += (size_t)NTOK*D_*2;
  f16* inner = (f16*)(ws + off); off += (size_t)NTOK*D_*2;
  f16* mid   = (f16*)(ws + off); off += (size_t)NTOK*M_*2;
  float* h   = (float*)(ws + off); off += (size_t)NTOK*D_*4;
  (void)ws_size; (void)in_sizes; (void)n_in; (void)out_size;

  // ---- scratch carved from the front of d_out (dead before head GEMM) ----
  char* ob = (char*)d_out;
  f16*   wT = (f16*)ob;                       // 4 layers x 12,582,912 f16 = 96.5 MB
  float* S  = (float*)(ob + 100663296);       // 32*1024*1024 fp32 = 134.2 MB
  f16*   P  = (f16*)  (ob + 234881024);       // 67.1 MB ; ends 302 MB < 412 MB

  const size_t wlsz = 12582912;  // elements per layer in wT
  const int64_t TD  = (int64_t)T_*D_;
  const int64_t TT  = (int64_t)T_*T_;
  const int64_t HTT = (int64_t)H_*TT;

  // ---- weight transposes (fp32 -> f16, [K,N] -> [N,K]) ----
  for (int l = 0; l < L_; ++l) {
    f16* qkvT_l = wT + l*wlsz;
    f16* outT_l = qkvT_l + (size_t)3*D_*D_;
    f16* wiT_l  = outT_l + (size_t)D_*D_;
    f16* woT_l  = wiT_l  + (size_t)D_*M_;
    transpose_w<<<dim3(3*D_/64, D_/64), 256, 0, stream>>>(qkv_w + (size_t)l*D_*3*D_, qkvT_l, D_, 3*D_);
    transpose_w<<<dim3(D_/64,   D_/64), 256, 0, stream>>>(out_w + (size_t)l*D_*D_,  outT_l, D_, D_);
    transpose_w<<<dim3(M_/64,   D_/64), 256, 0, stream>>>(wi_w  + (size_t)l*D_*M_,  wiT_l,  D_, M_);
    transpose_w<<<dim3(D_/64,   M_/64), 256, 0, stream>>>(wo_w  + (size_t)l*M_*D_,  woT_l,  M_, D_);
  }
  transpose_w<<<dim3((V_+63)/64, D_/64), 256, 0, stream>>>(head_w, headT, D_, V_);

  // ---- embedding ----
  embed_kernel<<<NTOK, 256, 0, stream>>>(x, tok_emb, pos_emb, h);

  // ---- layers ----
  for (int l = 0; l < L_; ++l) {
    f16* qkvT_l = wT + l*wlsz;
    f16* outT_l = qkvT_l + (size_t)3*D_*D_;
    f16* wiT_l  = outT_l + (size_t)D_*D_;
    f16* woT_l  = wiT_l  + (size_t)D_*M_;

    ln_kernel<<<NTOK, 256, 0, stream>>>(h, ln1_g + l*D_, ln1_b + l*D_, xbf);

    // qkv: [2048,1024] @ [1024,3072] -> qkvb f16 [2048,3072]
    gemm_bt<128,128,2,2,EPI_F16><<<dim3(3*D_/128, NTOK/128, 1), 256, 0, stream>>>(
        xbf, D_, qkvT_l, D_, qkvb, 3*D_, qkv_b + (size_t)l*3*D_, 3*D_, D_, 1.f,
        1, 0,0, 0,0, 0,0);

    transpose_v<<<dim3(T_/64, B_*H_), 256, 0, stream>>>(qkvb, vT);

    // scores: per (b,h): Q[1024,64] @ K^T -> S fp32, scaled by 1/8
    gemm_bt<128,128,2,2,EPI_F32><<<dim3(T_/128, T_/128, B_*H_), 256, 0, stream>>>(
        qkvb, D_, qkvb + (size_t)NTOK*D_, D_, S, T_, nullptr, T_, DH_, 0.125f,
        H_, TD, 64, TD, 64, HTT, TT);

    softmax_kernel<<<B_*H_*T_, 256, 0, stream>>>(S, P);

    // PV: per (b,h): P[1024,1024] @ V -> inner[b,t,h*64+dh] f16
    gemm_bt<128,64,4,1,EPI_F16><<<dim3(1, T_/128, B_*H_), 256, 0, stream>>>(
        P, T_, vT, T_, inner, D_, nullptr, DH_, T_, 1.f,
        H_, HTT, TT, (int64_t)H_*DH_*T_, (int64_t)DH_*T_, TD, 64);

    // out proj: h += inner @ out_w + out_b
    gemm_bt<128,64,4,1,EPI_ADDF32><<<dim3(D_/64, NTOK/128, 1), 256, 0, stream>>>(
        inner, D_, outT_l, D_, h, D_, out_b + (size_t)l*D_, D_, D_, 1.f,
        1, 0,0, 0,0, 0,0);

    ln_kernel<<<NTOK, 256, 0, stream>>>(h, ln2_g + l*D_, ln2_b + l*D_, xbf);

    // wi + exact GELU -> mid f16 [2048,4096]
    gemm_bt<128,128,2,2,EPI_GELU><<<dim3(M_/128, NTOK/128, 1), 256, 0, stream>>>(
        xbf, D_, wiT_l, D_, mid, M_, wi_b + (size_t)l*M_, M_, D_, 1.f,
        1, 0,0, 0,0, 0,0);

    // wo: h += mid @ wo_w + wo_b
    gemm_bt<128,64,4,1,EPI_ADDF32><<<dim3(D_/64, NTOK/128, 1), 256, 0, stream>>>(
        mid, M_, woT_l, M_, h, D_, wo_b + (size_t)l*D_, D_, M_, 1.f,
        1, 0,0, 0,0, 0,0);
  }

  // ---- final LN + head (writes all of d_out; scratch regions now dead) ----
  ln_kernel<<<NTOK, 256, 0, stream>>>(h, lnf_g, lnf_b, xbf);
  gemm_bt<128,128,2,2,EPI_F32><<<dim3((V_+127)/128, NTOK/128, 1), 256, 0, stream>>>(
      xbf, D_, headT, D_, out, V_, head_b, V_, D_, 1.f,
      1, 0,0, 0,0, 0,0);
}